// Round 1
// baseline (52.852 us; speedup 1.0000x reference)
//
#include <hip/hip_runtime.h>
#include <hip/hip_bf16.h>

#define BT 16      // B*T
#define NN 256     // nodes
#define DD 128     // feature dim
#define RPB 16     // rows per block in GEMM kernel

// ---------------- Kernel 0: compact adjacency into neighbor lists ----------
__global__ __launch_bounds__(64) void nbr_kernel(const float* __restrict__ adj,
                                                 int* __restrict__ nbr,
                                                 int* __restrict__ nbr_cnt) {
    int i = blockIdx.x;        // row
    int l = threadIdx.x;       // lane 0..63
    int cnt = 0;
    for (int jt = 0; jt < NN / 64; ++jt) {
        int j = jt * 64 + l;
        float v = adj[i * NN + j];
        unsigned long long mask = __ballot(v != 0.0f);
        if (v != 0.0f) {
            int pos = cnt + __popcll(mask & ((1ull << l) - 1ull));
            nbr[i * NN + pos] = j;
        }
        cnt += __popcll(mask);
    }
    if (l == 0) nbr_cnt[i] = cnt;
}

// ---------------- Kernel 1: h = x@W + bias; a = h@W1a; b = h@W1b + att_b1 --
__global__ __launch_bounds__(256) void hab_kernel(
        const float* __restrict__ x, const float* __restrict__ weight,
        const float* __restrict__ bias, const float* __restrict__ attw1,
        const float* __restrict__ attb1,
        float* __restrict__ hbuf, float* __restrict__ abuf, float* __restrict__ bbuf) {
    int chunk = blockIdx.x;    // 0..NN/RPB-1
    int bt    = blockIdx.y;    // 0..BT-1
    int row0  = chunk * RPB;
    int tid   = threadIdx.x;

    __shared__ float xs[RPB][DD];
    __shared__ float hs[RPB][DD];

    const float* xbase = x + (size_t)(bt * NN + row0) * DD;
    for (int idx = tid; idx < RPB * DD; idx += 256)
        xs[idx >> 7][idx & 127] = xbase[idx];
    __syncthreads();

    int d  = tid & 127;        // output column
    int rg = tid >> 7;         // row-group 0/1 (8 rows each)

    // h = x @ W + bias
    float acc[8];
#pragma unroll
    for (int r = 0; r < 8; ++r) acc[r] = 0.0f;
    for (int k = 0; k < DD; ++k) {
        float w = weight[k * DD + d];
#pragma unroll
        for (int r = 0; r < 8; ++r) acc[r] += xs[rg * 8 + r][k] * w;
    }
    float bv = bias[d];
    float* hout = hbuf + (size_t)(bt * NN + row0) * DD;
#pragma unroll
    for (int r = 0; r < 8; ++r) {
        float hv = acc[r] + bv;
        hs[rg * 8 + r][d] = hv;
        hout[(rg * 8 + r) * DD + d] = hv;
    }
    __syncthreads();

    // a = h @ W1a ; b = h @ W1b + att_b1   (att_w1 is (2D, D) row-major)
    float acca[8], accb[8];
#pragma unroll
    for (int r = 0; r < 8; ++r) { acca[r] = 0.0f; accb[r] = 0.0f; }
    for (int k = 0; k < DD; ++k) {
        float wa = attw1[k * DD + d];
        float wb = attw1[(k + DD) * DD + d];
#pragma unroll
        for (int r = 0; r < 8; ++r) {
            float hv = hs[rg * 8 + r][k];
            acca[r] += hv * wa;
            accb[r] += hv * wb;
        }
    }
    float b1 = attb1[d];
    float* aout = abuf + (size_t)(bt * NN + row0) * DD;
    float* bout = bbuf + (size_t)(bt * NN + row0) * DD;
#pragma unroll
    for (int r = 0; r < 8; ++r) {
        aout[(rg * 8 + r) * DD + d] = acca[r];
        bout[(rg * 8 + r) * DD + d] = accb[r] + b1;
    }
}

// ---------------- Kernel 2: sparse scores -> softmax -> aggregate -> LN ----
__global__ __launch_bounds__(64) void attn_kernel(
        const float* __restrict__ hbuf, const float* __restrict__ abuf,
        const float* __restrict__ bbuf, const float* __restrict__ x,
        const int* __restrict__ nbr, const int* __restrict__ nbr_cnt,
        const float* __restrict__ w2, const float* __restrict__ gamma,
        const float* __restrict__ beta, float* __restrict__ out) {
    int i  = blockIdx.x;       // node
    int bt = blockIdx.y;       // batch*time
    int l  = threadIdx.x;      // lane, owns dims l and l+64

    __shared__ float sw[NN];   // per-neighbor score -> weight

    int cnt = nbr_cnt[i];
    const float* arow = abuf + (size_t)(bt * NN + i) * DD;
    float a0 = arow[l], a1 = arow[l + 64];
    float w20 = w2[l],  w21 = w2[l + 64];

    float m = -3.0e38f;
    for (int c = 0; c < cnt; ++c) {
        int j = nbr[i * NN + c];
        const float* brow = bbuf + (size_t)(bt * NN + j) * DD;
        float e0 = a0 + brow[l];
        float e1 = a1 + brow[l + 64];
        e0 = e0 >= 0.0f ? e0 : 0.2f * e0;   // leaky_relu 0.2
        e1 = e1 >= 0.0f ? e1 : 0.2f * e1;
        float p = e0 * w20 + e1 * w21;
#pragma unroll
        for (int off = 32; off; off >>= 1) p += __shfl_xor(p, off);
        sw[c] = p;             // all lanes hold identical p
        m = fmaxf(m, p);
    }

    // softmax weights + denom
    float dsum = 0.0f;
    for (int c = l; c < cnt; c += 64) {
        float w = expf(sw[c] - m);
        sw[c] = w;
        dsum += w;
    }
#pragma unroll
    for (int off = 32; off; off >>= 1) dsum += __shfl_xor(dsum, off);
    float inv = 1.0f / dsum;

    // aggregate h rows
    float acc0 = 0.0f, acc1 = 0.0f;
    for (int c = 0; c < cnt; ++c) {
        float wgt = sw[c];
        int j = nbr[i * NN + c];
        const float* hrow = hbuf + (size_t)(bt * NN + j) * DD;
        acc0 += wgt * hrow[l];
        acc1 += wgt * hrow[l + 64];
    }

    const float* xrow = x + (size_t)(bt * NN + i) * DD;
    float y0 = acc0 * inv + xrow[l];
    float y1 = acc1 * inv + xrow[l + 64];

    // LayerNorm over 128 dims
    float s = y0 + y1;
#pragma unroll
    for (int off = 32; off; off >>= 1) s += __shfl_xor(s, off);
    float mu = s * (1.0f / 128.0f);
    float v0 = y0 - mu, v1 = y1 - mu;
    float vs = v0 * v0 + v1 * v1;
#pragma unroll
    for (int off = 32; off; off >>= 1) vs += __shfl_xor(vs, off);
    float rstd = rsqrtf(vs * (1.0f / 128.0f) + 1e-5f);

    float o0 = v0 * rstd * gamma[l]      + beta[l];
    float o1 = v1 * rstd * gamma[l + 64] + beta[l + 64];

    float* orow = out + (size_t)(bt * NN + i) * DD;
    orow[l]      = fmaxf(o0, 0.0f);
    orow[l + 64] = fmaxf(o1, 0.0f);
}

extern "C" void kernel_launch(void* const* d_in, const int* in_sizes, int n_in,
                              void* d_out, int out_size, void* d_ws, size_t ws_size,
                              hipStream_t stream) {
    const float* x      = (const float*)d_in[0];
    const float* adj    = (const float*)d_in[1];
    const float* weight = (const float*)d_in[2];
    const float* bias   = (const float*)d_in[3];
    const float* attw1  = (const float*)d_in[4];
    const float* attb1  = (const float*)d_in[5];
    const float* attw2  = (const float*)d_in[6];
    // d_in[7] = att_b2: uniform shift of all scores -> cancels in softmax
    const float* gamma  = (const float*)d_in[8];
    const float* beta   = (const float*)d_in[9];
    float* out = (float*)d_out;

    float* hbuf = (float*)d_ws;
    float* abuf = hbuf + (size_t)BT * NN * DD;
    float* bbuf = abuf + (size_t)BT * NN * DD;
    int*   nbr  = (int*)(bbuf + (size_t)BT * NN * DD);
    int*   nbr_cnt = nbr + NN * NN;

    nbr_kernel<<<NN, 64, 0, stream>>>(adj, nbr, nbr_cnt);
    hab_kernel<<<dim3(NN / RPB, BT), 256, 0, stream>>>(x, weight, bias, attw1, attb1,
                                                       hbuf, abuf, bbuf);
    attn_kernel<<<dim3(NN, BT), 64, 0, stream>>>(hbuf, abuf, bbuf, x, nbr, nbr_cnt,
                                                 attw2, gamma, beta, out);
}

// Round 2
// 40.491 us; speedup vs baseline: 1.3053x; 1.3053x over previous
//
#include <hip/hip_runtime.h>
#include <hip/hip_bf16.h>

#define BT 16      // B*T
#define NN 256     // nodes
#define DD 128     // feature dim
#define MROWS (BT*NN)   // 4096 total rows

typedef __bf16 bf16x8 __attribute__((ext_vector_type(8)));
typedef float  f32x4  __attribute__((ext_vector_type(4)));

// ---- prep kernel block-role layout ----
#define WCOMB_B 64                      // combined-weight blocks (2 k-rows each)
#define WT_B    16                      // W-transpose blocks (8 k-rows each)
#define XBF_B   128                     // x -> bf16 blocks
#define NBR_B   16                      // adjacency compaction blocks
#define R_WT0   WCOMB_B                 // 64
#define R_XBF0  (WCOMB_B + WT_B)        // 80
#define R_NBR0  (R_XBF0 + XBF_B)        // 208
#define R_BIAS  (R_NBR0 + NBR_B)        // 224
#define PREP_BLOCKS (R_BIAS + 1)        // 225

// ================= Kernel 0: prep (nbr lists, bf16 casts, weight fusion) ===
// Bt is the 384x128 bf16 B^T for the fused GEMM:
//   rows [0,128)   : W^T                (h   = x@W + bias)
//   rows [128,256) : (W@W1a)^T          (a   = x@W@W1a + bias@W1a)
//   rows [256,384) : (W@W1b)^T          (b   = x@W@W1b + bias@W1b + att_b1)
// bias_full[384] holds the matching output biases.
__global__ __launch_bounds__(256) void prep_kernel(
        const float* __restrict__ x, const float* __restrict__ adj,
        const float* __restrict__ weight, const float* __restrict__ bias,
        const float* __restrict__ attw1, const float* __restrict__ attb1,
        __bf16* __restrict__ x_bf, __bf16* __restrict__ Bt,
        float* __restrict__ bias_full, int* __restrict__ nbr,
        int* __restrict__ nbr_cnt) {
    int b = blockIdx.x, tid = threadIdx.x;
    if (b < WCOMB_B) {
        // combined weights, fp32 dot then one bf16 quantization
        int k0 = 2 * b;
        int half = tid >> 7;            // 0 -> W1a, 1 -> W1b
        int n = tid & 127;
        const float* w1col = attw1 + (size_t)(half * DD) * DD + n;
        const float* wr0 = weight + (size_t)k0 * DD;
        const float* wr1 = wr0 + DD;
        float acc0 = 0.f, acc1 = 0.f;
        for (int m = 0; m < DD; ++m) {
            float wx = w1col[(size_t)m * DD];   // coalesced across tid
            acc0 += wr0[m] * wx;                // broadcast
            acc1 += wr1[m] * wx;
        }
        Bt[(size_t)(DD + tid) * DD + k0]     = (__bf16)acc0;
        Bt[(size_t)(DD + tid) * DD + k0 + 1] = (__bf16)acc1;
    } else if (b < R_XBF0) {
        // Bt[n][k] = W[k][n] for n < 128
        int k0 = (b - R_WT0) * 8;
        int n = tid & 127, dk = tid >> 7;
        for (int p = 0; p < 4; ++p) {
            int k = k0 + p * 2 + dk;
            Bt[(size_t)n * DD + k] = (__bf16)weight[(size_t)k * DD + n];
        }
    } else if (b < R_NBR0) {
        // x (fp32) -> x_bf (bf16), vectorized
        const float4* x4 = (const float4*)x;
        int base = (b - R_XBF0) * 1024;
        for (int p = 0; p < 4; ++p) {
            int g = base + p * 256 + tid;
            float4 v = x4[g];
            union { ushort4 u; __bf16 h[4]; } pk;
            pk.h[0] = (__bf16)v.x; pk.h[1] = (__bf16)v.y;
            pk.h[2] = (__bf16)v.z; pk.h[3] = (__bf16)v.w;
            ((ushort4*)x_bf)[g] = pk.u;
        }
    } else if (b < R_BIAS) {
        // neighbor-list compaction, one wave handles 4 rows
        int w = tid >> 6, l = tid & 63;
        for (int r = 0; r < 4; ++r) {
            int i = (b - R_NBR0) * 16 + w * 4 + r;
            int cnt = 0;
            for (int jt = 0; jt < NN / 64; ++jt) {
                int j = jt * 64 + l;
                float v = adj[(size_t)i * NN + j];
                unsigned long long mask = __ballot(v != 0.f);
                if (v != 0.f) {
                    int pos = cnt + __popcll(mask & ((1ull << l) - 1ull));
                    nbr[i * NN + pos] = j;
                }
                cnt += __popcll(mask);
            }
            if (l == 0) nbr_cnt[i] = cnt;
        }
    } else {
        // bias_full
        int half = tid >> 7, n = tid & 127;
        const float* w1col = attw1 + (size_t)(half * DD) * DD + n;
        float acc = 0.f;
        for (int k = 0; k < DD; ++k) acc += bias[k] * w1col[(size_t)k * DD];
        if (half) acc += attb1[n];
        bias_full[DD + tid] = acc;
        if (tid < DD) bias_full[tid] = bias[tid];
    }
}

// ================= Kernel 1: fused GEMM via MFMA ===========================
// C[4096 x 384] = x_bf @ Bt^T (+bias_full), split-stored to hbuf/abuf/bbuf.
// Block: 16 rows, 4 waves; wave w owns 16-col tiles t = w, w+4, ..., w+20.
__global__ __launch_bounds__(256) void gemm_kernel(
        const __bf16* __restrict__ x_bf, const __bf16* __restrict__ Bt,
        const float* __restrict__ bias_full,
        float* __restrict__ hbuf, float* __restrict__ abuf,
        float* __restrict__ bbuf) {
    int tid = threadIdx.x;
    int w = tid >> 6, l = tid & 63;
    int row0 = blockIdx.x * 16;
    int lrow = l & 15, lk = (l >> 4) * 8;

    // A fragments: lane holds row (l&15), k = (l>>4)*8 + j  (+32 per k-tile)
    const __bf16* abase = x_bf + (size_t)(row0 + lrow) * DD + lk;
    bf16x8 af0 = *(const bf16x8*)(abase);
    bf16x8 af1 = *(const bf16x8*)(abase + 32);
    bf16x8 af2 = *(const bf16x8*)(abase + 64);
    bf16x8 af3 = *(const bf16x8*)(abase + 96);

#pragma unroll
    for (int t6 = 0; t6 < 6; ++t6) {
        int t = w + 4 * t6;
        int n0 = t * 16;
        const __bf16* bbase = Bt + (size_t)(n0 + lrow) * DD + lk;
        f32x4 acc = {0.f, 0.f, 0.f, 0.f};
        acc = __builtin_amdgcn_mfma_f32_16x16x32_bf16(af0, *(const bf16x8*)(bbase),      acc, 0, 0, 0);
        acc = __builtin_amdgcn_mfma_f32_16x16x32_bf16(af1, *(const bf16x8*)(bbase + 32), acc, 0, 0, 0);
        acc = __builtin_amdgcn_mfma_f32_16x16x32_bf16(af2, *(const bf16x8*)(bbase + 64), acc, 0, 0, 0);
        acc = __builtin_amdgcn_mfma_f32_16x16x32_bf16(af3, *(const bf16x8*)(bbase + 96), acc, 0, 0, 0);

        float bb = bias_full[n0 + lrow];
        float* dst = (t < 8) ? hbuf : (t < 16) ? abuf : bbuf;
        int nloc = (n0 & 127) + lrow;           // C/D: col = lane&15
        int rbase = row0 + (l >> 4) * 4;        //      row = (lane>>4)*4 + reg
        dst[(size_t)(rbase + 0) * DD + nloc] = acc[0] + bb;
        dst[(size_t)(rbase + 1) * DD + nloc] = acc[1] + bb;
        dst[(size_t)(rbase + 2) * DD + nloc] = acc[2] + bb;
        dst[(size_t)(rbase + 3) * DD + nloc] = acc[3] + bb;
    }
}

// ================= Kernel 2: sparse attn + LayerNorm + ReLU ================
// 4 waves/block, one node per wave. Neighbor indices and softmax weights
// live entirely in registers (lane c owns neighbor c).
__global__ __launch_bounds__(256) void attn_kernel(
        const float* __restrict__ hbuf, const float* __restrict__ abuf,
        const float* __restrict__ bbuf, const float* __restrict__ x,
        const int* __restrict__ nbr, const int* __restrict__ nbr_cnt,
        const float* __restrict__ w2, const float* __restrict__ gamma,
        const float* __restrict__ beta, float* __restrict__ out) {
    int tid = threadIdx.x;
    int w = tid >> 6, l = tid & 63;
    int i = blockIdx.x * 4 + w;
    int bt = blockIdx.y;

    int cnt = nbr_cnt[i];
    int jreg = nbr[i * NN + l];     // lane l holds neighbor l's index (valid l<cnt)

    const float* arow = abuf + (size_t)(bt * NN + i) * DD;
    float a0 = arow[l], a1 = arow[l + 64];
    float w20 = w2[l],  w21 = w2[l + 64];

    float m = -3.0e38f, myp = 0.f;
    int c = 0;
    for (; c + 1 < cnt; c += 2) {   // 2-way ILP on the reduce chains
        int j0 = __shfl(jreg, c);
        int j1 = __shfl(jreg, c + 1);
        const float* b0 = bbuf + (size_t)(bt * NN + j0) * DD;
        const float* b1 = bbuf + (size_t)(bt * NN + j1) * DD;
        float e00 = a0 + b0[l], e01 = a1 + b0[l + 64];
        float e10 = a0 + b1[l], e11 = a1 + b1[l + 64];
        e00 = e00 >= 0.f ? e00 : 0.2f * e00;
        e01 = e01 >= 0.f ? e01 : 0.2f * e01;
        e10 = e10 >= 0.f ? e10 : 0.2f * e10;
        e11 = e11 >= 0.f ? e11 : 0.2f * e11;
        float p0 = e00 * w20 + e01 * w21;
        float p1 = e10 * w20 + e11 * w21;
#pragma unroll
        for (int off = 32; off; off >>= 1) {
            p0 += __shfl_xor(p0, off);
            p1 += __shfl_xor(p1, off);
        }
        myp = (l == c)     ? p0 : myp;
        myp = (l == c + 1) ? p1 : myp;
        m = fmaxf(m, fmaxf(p0, p1));
    }
    if (c < cnt) {
        int j0 = __shfl(jreg, c);
        const float* b0 = bbuf + (size_t)(bt * NN + j0) * DD;
        float e00 = a0 + b0[l], e01 = a1 + b0[l + 64];
        e00 = e00 >= 0.f ? e00 : 0.2f * e00;
        e01 = e01 >= 0.f ? e01 : 0.2f * e01;
        float p0 = e00 * w20 + e01 * w21;
#pragma unroll
        for (int off = 32; off; off >>= 1) p0 += __shfl_xor(p0, off);
        myp = (l == c) ? p0 : myp;
        m = fmaxf(m, p0);
    }

    float wgt = (l < cnt) ? expf(myp - m) : 0.f;
    float dsum = wgt;
#pragma unroll
    for (int off = 32; off; off >>= 1) dsum += __shfl_xor(dsum, off);
    float inv = 1.f / dsum;

    float acc0 = 0.f, acc1 = 0.f;
    for (c = 0; c < cnt; ++c) {
        float wc = __shfl(wgt, c);
        int j = __shfl(jreg, c);
        const float* hrow = hbuf + (size_t)(bt * NN + j) * DD;
        acc0 += wc * hrow[l];
        acc1 += wc * hrow[l + 64];
    }

    const float* xrow = x + (size_t)(bt * NN + i) * DD;
    float y0 = acc0 * inv + xrow[l];
    float y1 = acc1 * inv + xrow[l + 64];

    float s = y0 + y1;
#pragma unroll
    for (int off = 32; off; off >>= 1) s += __shfl_xor(s, off);
    float mu = s * (1.0f / 128.0f);
    float v0 = y0 - mu, v1 = y1 - mu;
    float vs = v0 * v0 + v1 * v1;
#pragma unroll
    for (int off = 32; off; off >>= 1) vs += __shfl_xor(vs, off);
    float rstd = rsqrtf(vs * (1.0f / 128.0f) + 1e-5f);

    float o0 = v0 * rstd * gamma[l]      + beta[l];
    float o1 = v1 * rstd * gamma[l + 64] + beta[l + 64];

    float* orow = out + (size_t)(bt * NN + i) * DD;
    orow[l]      = fmaxf(o0, 0.0f);
    orow[l + 64] = fmaxf(o1, 0.0f);
}

extern "C" void kernel_launch(void* const* d_in, const int* in_sizes, int n_in,
                              void* d_out, int out_size, void* d_ws, size_t ws_size,
                              hipStream_t stream) {
    const float* x      = (const float*)d_in[0];
    const float* adj    = (const float*)d_in[1];
    const float* weight = (const float*)d_in[2];
    const float* bias   = (const float*)d_in[3];
    const float* attw1  = (const float*)d_in[4];
    const float* attb1  = (const float*)d_in[5];
    const float* attw2  = (const float*)d_in[6];
    // d_in[7] = att_b2: uniform score shift -> cancels in softmax
    const float* gamma  = (const float*)d_in[8];
    const float* beta   = (const float*)d_in[9];
    float* out = (float*)d_out;

    char* p = (char*)d_ws;
    float* hbuf = (float*)p;          p += (size_t)MROWS * DD * 4;
    float* abuf = (float*)p;          p += (size_t)MROWS * DD * 4;
    float* bbuf = (float*)p;          p += (size_t)MROWS * DD * 4;
    float* bias_full = (float*)p;     p += 512 * 4;
    __bf16* x_bf = (__bf16*)p;        p += (size_t)MROWS * DD * 2;
    __bf16* Bt   = (__bf16*)p;        p += (size_t)384 * DD * 2;
    int* nbr     = (int*)p;           p += (size_t)NN * NN * 4;
    int* nbr_cnt = (int*)p;

    prep_kernel<<<PREP_BLOCKS, 256, 0, stream>>>(x, adj, weight, bias, attw1, attb1,
                                                 x_bf, Bt, bias_full, nbr, nbr_cnt);
    gemm_kernel<<<MROWS / 16, 256, 0, stream>>>(x_bf, Bt, bias_full, hbuf, abuf, bbuf);
    attn_kernel<<<dim3(NN / 4, BT), 256, 0, stream>>>(hbuf, abuf, bbuf, x, nbr, nbr_cnt,
                                                      attw2, gamma, beta, out);
}

// Round 4
// 34.638 us; speedup vs baseline: 1.5258x; 1.1690x over previous
//
#include <hip/hip_runtime.h>
#include <hip/hip_bf16.h>

#define BT 16      // B*T
#define NN 256     // nodes
#define DD 128     // feature dim
#define MROWS (BT*NN)   // 4096 total rows

typedef __bf16 bf16x8 __attribute__((ext_vector_type(8)));
typedef float  f32x4  __attribute__((ext_vector_type(4)));

#define LREL(z) ((z) >= 0.0f ? (z) : 0.2f * (z))

// prep roles: 64 WCOMB + 16 WT + 16 NBR + 1 bias = 97 blocks
#define PREP_BLOCKS 97

// ================= Kernel 0: prep (weight fusion, nbr lists, bias) =========
// Bt is the 384x128 bf16 B^T for the fused GEMM:
//   rows [0,128)   : W^T        (h = x@W + bias)
//   rows [128,256) : (W@W1a)^T  (a = x@(W@W1a) + bias@W1a)
//   rows [256,384) : (W@W1b)^T  (b = x@(W@W1b) + bias@W1b + att_b1)
__global__ __launch_bounds__(256) void prep_kernel(
        const float* __restrict__ weight, const float* __restrict__ bias,
        const float* __restrict__ attw1, const float* __restrict__ attb1,
        const float* __restrict__ adj,
        __bf16* __restrict__ Bt, float* __restrict__ bias_full,
        int* __restrict__ nbr, int* __restrict__ nbr_cnt) {
    int b = blockIdx.x, tid = threadIdx.x;
    if (b < 64) {
        // combined weights: fp32 dot, single bf16 quantization
        int k0 = 2 * b;
        int half = tid >> 7;            // 0 -> W1a, 1 -> W1b
        int n = tid & 127;
        const float* w1col = attw1 + (size_t)(half * DD) * DD + n;
        const float* wr0 = weight + (size_t)k0 * DD;
        const float* wr1 = wr0 + DD;
        float acc0 = 0.f, acc1 = 0.f;
        for (int m = 0; m < DD; ++m) {
            float wx = w1col[(size_t)m * DD];   // coalesced across tid
            acc0 += wr0[m] * wx;
            acc1 += wr1[m] * wx;
        }
        Bt[(size_t)(DD + tid) * DD + k0]     = (__bf16)acc0;
        Bt[(size_t)(DD + tid) * DD + k0 + 1] = (__bf16)acc1;
    } else if (b < 80) {
        // Bt[n][k] = W[k][n] for n < 128
        int k0 = (b - 64) * 8;
        int n = tid & 127, dk = tid >> 7;
        for (int p = 0; p < 4; ++p) {
            int k = k0 + p * 2 + dk;
            Bt[(size_t)n * DD + k] = (__bf16)weight[(size_t)k * DD + n];
        }
    } else if (b < 96) {
        // neighbor-list compaction, one wave handles 4 rows
        int w = tid >> 6, l = tid & 63;
        for (int r = 0; r < 4; ++r) {
            int i = (b - 80) * 16 + w * 4 + r;
            int cnt = 0;
            for (int jt = 0; jt < NN / 64; ++jt) {
                int j = jt * 64 + l;
                float v = adj[(size_t)i * NN + j];
                unsigned long long mask = __ballot(v != 0.f);
                if (v != 0.f) {
                    int pos = cnt + __popcll(mask & ((1ull << l) - 1ull));
                    nbr[i * NN + pos] = j;
                }
                cnt += __popcll(mask);
            }
            if (l == 0) nbr_cnt[i] = cnt;
        }
    } else {
        // bias_full[384]
        int half = tid >> 7, n = tid & 127;
        const float* w1col = attw1 + (size_t)(half * DD) * DD + n;
        float acc = 0.f;
        for (int k = 0; k < DD; ++k) acc += bias[k] * w1col[(size_t)k * DD];
        if (half) acc += attb1[n];
        bias_full[DD + tid] = acc;
        if (tid < DD) bias_full[tid] = bias[tid];
    }
}

// ================= Kernel 1: fused GEMM via MFMA ===========================
// C[4096 x 384] = x @ Bt^T (+bias_full), split-stored to hbuf/abuf/bbuf.
// x loaded fp32 and converted to bf16 fragments in-register (x read once).
__global__ __launch_bounds__(256) void gemm_kernel(
        const float* __restrict__ x, const __bf16* __restrict__ Bt,
        const float* __restrict__ bias_full,
        float* __restrict__ hbuf, float* __restrict__ abuf,
        float* __restrict__ bbuf) {
    int tid = threadIdx.x;
    int w = tid >> 6, l = tid & 63;
    int row0 = blockIdx.x * 16;
    int lrow = l & 15, lk = (l >> 4) * 8;

    // A fragments: lane holds row (l&15), k = (l>>4)*8 + j  (+32 per k-tile)
    const float* abase = x + (size_t)(row0 + lrow) * DD + lk;
    bf16x8 af0, af1, af2, af3;
    {
        float4 u0, u1;
        u0 = *(const float4*)(abase +  0); u1 = *(const float4*)(abase +  4);
        af0[0]=(__bf16)u0.x; af0[1]=(__bf16)u0.y; af0[2]=(__bf16)u0.z; af0[3]=(__bf16)u0.w;
        af0[4]=(__bf16)u1.x; af0[5]=(__bf16)u1.y; af0[6]=(__bf16)u1.z; af0[7]=(__bf16)u1.w;
        u0 = *(const float4*)(abase + 32); u1 = *(const float4*)(abase + 36);
        af1[0]=(__bf16)u0.x; af1[1]=(__bf16)u0.y; af1[2]=(__bf16)u0.z; af1[3]=(__bf16)u0.w;
        af1[4]=(__bf16)u1.x; af1[5]=(__bf16)u1.y; af1[6]=(__bf16)u1.z; af1[7]=(__bf16)u1.w;
        u0 = *(const float4*)(abase + 64); u1 = *(const float4*)(abase + 68);
        af2[0]=(__bf16)u0.x; af2[1]=(__bf16)u0.y; af2[2]=(__bf16)u0.z; af2[3]=(__bf16)u0.w;
        af2[4]=(__bf16)u1.x; af2[5]=(__bf16)u1.y; af2[6]=(__bf16)u1.z; af2[7]=(__bf16)u1.w;
        u0 = *(const float4*)(abase + 96); u1 = *(const float4*)(abase + 100);
        af3[0]=(__bf16)u0.x; af3[1]=(__bf16)u0.y; af3[2]=(__bf16)u0.z; af3[3]=(__bf16)u0.w;
        af3[4]=(__bf16)u1.x; af3[5]=(__bf16)u1.y; af3[6]=(__bf16)u1.z; af3[7]=(__bf16)u1.w;
    }

#pragma unroll
    for (int t6 = 0; t6 < 6; ++t6) {
        int t = w + 4 * t6;
        int n0 = t * 16;
        const __bf16* bbase = Bt + (size_t)(n0 + lrow) * DD + lk;
        f32x4 acc = {0.f, 0.f, 0.f, 0.f};
        acc = __builtin_amdgcn_mfma_f32_16x16x32_bf16(af0, *(const bf16x8*)(bbase),      acc, 0, 0, 0);
        acc = __builtin_amdgcn_mfma_f32_16x16x32_bf16(af1, *(const bf16x8*)(bbase + 32), acc, 0, 0, 0);
        acc = __builtin_amdgcn_mfma_f32_16x16x32_bf16(af2, *(const bf16x8*)(bbase + 64), acc, 0, 0, 0);
        acc = __builtin_amdgcn_mfma_f32_16x16x32_bf16(af3, *(const bf16x8*)(bbase + 96), acc, 0, 0, 0);

        float bb = bias_full[n0 + lrow];
        float* dst = (t < 8) ? hbuf : (t < 16) ? abuf : bbuf;
        int nloc = (n0 & 127) + lrow;           // C/D: col = lane&15
        int rbase = row0 + (l >> 4) * 4;        //      row = (lane>>4)*4 + reg
        dst[(size_t)(rbase + 0) * DD + nloc] = acc[0] + bb;
        dst[(size_t)(rbase + 1) * DD + nloc] = acc[1] + bb;
        dst[(size_t)(rbase + 2) * DD + nloc] = acc[2] + bb;
        dst[(size_t)(rbase + 3) * DD + nloc] = acc[3] + bb;
    }
}

// ================= Kernel 2: sparse attn + LayerNorm + ReLU ================
// 4 waves/block, one (node, bt) per wave; lane l owns dims l and l+64.
// Round-2 proven skeleton, widened to 4-way ILP.
__global__ __launch_bounds__(256) void attn_kernel(
        const float* __restrict__ hbuf, const float* __restrict__ abuf,
        const float* __restrict__ bbuf, const float* __restrict__ x,
        const int* __restrict__ nbr, const int* __restrict__ nbr_cnt,
        const float* __restrict__ w2, const float* __restrict__ gamma,
        const float* __restrict__ beta, float* __restrict__ out) {
    int tid = threadIdx.x;
    int w = tid >> 6, l = tid & 63;
    int i = blockIdx.x * 4 + w;
    int bt = blockIdx.y;

    int cnt = nbr_cnt[i];
    int jreg = nbr[i * NN + l];     // lane l holds neighbor l's index (valid l<cnt)

    const float* arow = abuf + (size_t)(bt * NN + i) * DD;
    float a0 = arow[l], a1 = arow[l + 64];
    float w20 = w2[l],  w21 = w2[l + 64];
    const float* bbase = bbuf + (size_t)bt * NN * DD;

    // ---- scores: 4 neighbors per iteration (4 independent reduce chains) ----
    float m = -3.0e38f, myp = 0.f;
    int c = 0;
    for (; c + 3 < cnt; c += 4) {
        int j0 = __shfl(jreg, c);
        int j1 = __shfl(jreg, c + 1);
        int j2 = __shfl(jreg, c + 2);
        int j3 = __shfl(jreg, c + 3);
        const float* B0 = bbase + (size_t)j0 * DD;
        const float* B1 = bbase + (size_t)j1 * DD;
        const float* B2 = bbase + (size_t)j2 * DD;
        const float* B3 = bbase + (size_t)j3 * DD;
        float p0 = LREL(a0 + B0[l]) * w20 + LREL(a1 + B0[l + 64]) * w21;
        float p1 = LREL(a0 + B1[l]) * w20 + LREL(a1 + B1[l + 64]) * w21;
        float p2 = LREL(a0 + B2[l]) * w20 + LREL(a1 + B2[l + 64]) * w21;
        float p3 = LREL(a0 + B3[l]) * w20 + LREL(a1 + B3[l + 64]) * w21;
#pragma unroll
        for (int off = 32; off; off >>= 1) {
            p0 += __shfl_xor(p0, off);
            p1 += __shfl_xor(p1, off);
            p2 += __shfl_xor(p2, off);
            p3 += __shfl_xor(p3, off);
        }
        myp = (l == c)     ? p0 : myp;
        myp = (l == c + 1) ? p1 : myp;
        myp = (l == c + 2) ? p2 : myp;
        myp = (l == c + 3) ? p3 : myp;
        m = fmaxf(m, fmaxf(fmaxf(p0, p1), fmaxf(p2, p3)));
    }
    for (; c < cnt; ++c) {
        int j0 = __shfl(jreg, c);
        const float* B0 = bbase + (size_t)j0 * DD;
        float p0 = LREL(a0 + B0[l]) * w20 + LREL(a1 + B0[l + 64]) * w21;
#pragma unroll
        for (int off = 32; off; off >>= 1) p0 += __shfl_xor(p0, off);
        myp = (l == c) ? p0 : myp;
        m = fmaxf(m, p0);
    }

    float wgt = (l < cnt) ? expf(myp - m) : 0.f;
    float dsum = wgt;
#pragma unroll
    for (int off = 32; off; off >>= 1) dsum += __shfl_xor(dsum, off);
    float inv = 1.f / dsum;

    // ---- aggregate: 4 neighbors per iteration ----
    const float* hbase = hbuf + (size_t)bt * NN * DD;
    float acc0 = 0.f, acc1 = 0.f;
    c = 0;
    for (; c + 3 < cnt; c += 4) {
        float wc0 = __shfl(wgt, c),     wc1 = __shfl(wgt, c + 1);
        float wc2 = __shfl(wgt, c + 2), wc3 = __shfl(wgt, c + 3);
        int j0 = __shfl(jreg, c),     j1 = __shfl(jreg, c + 1);
        int j2 = __shfl(jreg, c + 2), j3 = __shfl(jreg, c + 3);
        const float* H0 = hbase + (size_t)j0 * DD;
        const float* H1 = hbase + (size_t)j1 * DD;
        const float* H2 = hbase + (size_t)j2 * DD;
        const float* H3 = hbase + (size_t)j3 * DD;
        acc0 += wc0 * H0[l]      + wc1 * H1[l]      + wc2 * H2[l]      + wc3 * H3[l];
        acc1 += wc0 * H0[l + 64] + wc1 * H1[l + 64] + wc2 * H2[l + 64] + wc3 * H3[l + 64];
    }
    for (; c < cnt; ++c) {
        float wc = __shfl(wgt, c);
        int j = __shfl(jreg, c);
        const float* H = hbase + (size_t)j * DD;
        acc0 += wc * H[l];
        acc1 += wc * H[l + 64];
    }

    // ---- residual + LayerNorm + ReLU (round-2 verbatim) ----
    const float* xrow = x + (size_t)(bt * NN + i) * DD;
    float y0 = acc0 * inv + xrow[l];
    float y1 = acc1 * inv + xrow[l + 64];

    float s = y0 + y1;
#pragma unroll
    for (int off = 32; off; off >>= 1) s += __shfl_xor(s, off);
    float mu = s * (1.0f / 128.0f);
    float v0 = y0 - mu, v1 = y1 - mu;
    float vs = v0 * v0 + v1 * v1;
#pragma unroll
    for (int off = 32; off; off >>= 1) vs += __shfl_xor(vs, off);
    float rstd = rsqrtf(vs * (1.0f / 128.0f) + 1e-5f);

    float o0 = v0 * rstd * gamma[l]      + beta[l];
    float o1 = v1 * rstd * gamma[l + 64] + beta[l + 64];

    float* orow = out + (size_t)(bt * NN + i) * DD;
    orow[l]      = fmaxf(o0, 0.0f);
    orow[l + 64] = fmaxf(o1, 0.0f);
}

extern "C" void kernel_launch(void* const* d_in, const int* in_sizes, int n_in,
                              void* d_out, int out_size, void* d_ws, size_t ws_size,
                              hipStream_t stream) {
    const float* x      = (const float*)d_in[0];
    const float* adj    = (const float*)d_in[1];
    const float* weight = (const float*)d_in[2];
    const float* bias   = (const float*)d_in[3];
    const float* attw1  = (const float*)d_in[4];
    const float* attb1  = (const float*)d_in[5];
    const float* attw2  = (const float*)d_in[6];
    // d_in[7] = att_b2: uniform score shift -> cancels in softmax
    const float* gamma  = (const float*)d_in[8];
    const float* beta   = (const float*)d_in[9];
    float* out = (float*)d_out;

    char* p = (char*)d_ws;
    float* hbuf = (float*)p;          p += (size_t)MROWS * DD * 4;
    float* abuf = (float*)p;          p += (size_t)MROWS * DD * 4;
    float* bbuf = (float*)p;          p += (size_t)MROWS * DD * 4;
    float* bias_full = (float*)p;     p += 512 * 4;
    __bf16* Bt = (__bf16*)p;          p += (size_t)384 * DD * 2;
    int* nbr     = (int*)p;           p += (size_t)NN * NN * 4;
    int* nbr_cnt = (int*)p;

    prep_kernel<<<PREP_BLOCKS, 256, 0, stream>>>(weight, bias, attw1, attb1, adj,
                                                 Bt, bias_full, nbr, nbr_cnt);
    gemm_kernel<<<MROWS / 16, 256, 0, stream>>>(x, Bt, bias_full, hbuf, abuf, bbuf);
    attn_kernel<<<dim3(NN / 4, BT), 256, 0, stream>>>(hbuf, abuf, bbuf, x, nbr, nbr_cnt,
                                                      attw2, gamma, beta, out);
}

// Round 5
// 33.872 us; speedup vs baseline: 1.5603x; 1.0226x over previous
//
#include <hip/hip_runtime.h>
#include <hip/hip_bf16.h>

#define BT 16      // B*T
#define NN 256     // nodes
#define DD 128     // feature dim
#define MROWS (BT*NN)   // 4096 total rows

typedef __bf16 bf16x8 __attribute__((ext_vector_type(8)));
typedef float  f32x4  __attribute__((ext_vector_type(4)));

#define LREL(z) ((z) >= 0.0f ? (z) : 0.2f * (z))

// prep roles: 32 MFMA-comb + 16 WT + 16 NBR + 1 bias = 65 blocks
#define PREP_BLOCKS 65

// ================= Kernel 0: prep (weight fusion, nbr lists, bias) =========
// Bt is the 384x128 bf16 B^T for the fused GEMM:
//   rows [0,128)   : W^T        (h = x@W + bias)
//   rows [128,256) : (W@W1a)^T  (a = x@(W@W1a) + bias@W1a)
//   rows [256,384) : (W@W1b)^T  (b = x@(W@W1b) + bias@W1b + att_b1)
// Combined weights computed via MFMA: D[n2][k] = sum_m attw1[half*128+m][n] * weight[k][m]
__global__ __launch_bounds__(256) void prep_kernel(
        const float* __restrict__ weight, const float* __restrict__ bias,
        const float* __restrict__ attw1, const float* __restrict__ attb1,
        const float* __restrict__ adj,
        __bf16* __restrict__ Bt, float* __restrict__ bias_full,
        int* __restrict__ nbr, int* __restrict__ nbr_cnt) {
    int b = blockIdx.x, tid = threadIdx.x;
    if (b < 32) {
        // ---- combined weights via MFMA: 128 tiles of 16(n2) x 16(k), K=128 ----
        int w = tid >> 6, l = tid & 63;
        int idx = b * 4 + w;            // tile id 0..127
        int kt_t = idx & 7;             // k-tile
        int nt_t = idx >> 3;            // n2-tile
        int k0 = kt_t * 16, n0 = nt_t * 16;
        int lrow = l & 15, lk8 = (l >> 4) * 8;

        int n2 = n0 + lrow;
        int half = n2 >> 7, ncol = n2 & 127;

        // A-frag: lane row = n2, contracted elems m = lk8 + 32*kt + j
        // attw1[(half*128 + m)][ncol] -- strided scalar loads (L2-hot, tiny)
        bf16x8 Af[4];
#pragma unroll
        for (int kt = 0; kt < 4; ++kt) {
            const float* ap = attw1 + (size_t)(half * DD + lk8 + 32 * kt) * DD + ncol;
#pragma unroll
            for (int j = 0; j < 8; ++j)
                Af[kt][j] = (__bf16)ap[(size_t)j * DD];
        }
        // B-frag: lane col = k (weight row k), contracted elems m contiguous
        const float* wrow = weight + (size_t)(k0 + lrow) * DD + lk8;
        bf16x8 Bf[4];
#pragma unroll
        for (int kt = 0; kt < 4; ++kt) {
            float4 u0 = *(const float4*)(wrow + 32 * kt);
            float4 u1 = *(const float4*)(wrow + 32 * kt + 4);
            Bf[kt][0]=(__bf16)u0.x; Bf[kt][1]=(__bf16)u0.y;
            Bf[kt][2]=(__bf16)u0.z; Bf[kt][3]=(__bf16)u0.w;
            Bf[kt][4]=(__bf16)u1.x; Bf[kt][5]=(__bf16)u1.y;
            Bf[kt][6]=(__bf16)u1.z; Bf[kt][7]=(__bf16)u1.w;
        }
        f32x4 acc = {0.f, 0.f, 0.f, 0.f};
        acc = __builtin_amdgcn_mfma_f32_16x16x32_bf16(Af[0], Bf[0], acc, 0, 0, 0);
        acc = __builtin_amdgcn_mfma_f32_16x16x32_bf16(Af[1], Bf[1], acc, 0, 0, 0);
        acc = __builtin_amdgcn_mfma_f32_16x16x32_bf16(Af[2], Bf[2], acc, 0, 0, 0);
        acc = __builtin_amdgcn_mfma_f32_16x16x32_bf16(Af[3], Bf[3], acc, 0, 0, 0);

        // D: col = lane&15 -> k, row = (lane>>4)*4 + r -> n2
        int kcol = k0 + lrow;
        int nrow = n0 + (l >> 4) * 4;
#pragma unroll
        for (int r = 0; r < 4; ++r)
            Bt[(size_t)(DD + nrow + r) * DD + kcol] = (__bf16)acc[r];
    } else if (b < 48) {
        // Bt[n][k] = W[k][n] for n < 128
        int k0 = (b - 32) * 8;
        int n = tid & 127, dk = tid >> 7;
        for (int p = 0; p < 4; ++p) {
            int k = k0 + p * 2 + dk;
            Bt[(size_t)n * DD + k] = (__bf16)weight[(size_t)k * DD + n];
        }
    } else if (b < 64) {
        // neighbor-list compaction, one wave handles 4 rows
        int w = tid >> 6, l = tid & 63;
        for (int r = 0; r < 4; ++r) {
            int i = (b - 48) * 16 + w * 4 + r;
            int cnt = 0;
            for (int jt = 0; jt < NN / 64; ++jt) {
                int j = jt * 64 + l;
                float v = adj[(size_t)i * NN + j];
                unsigned long long mask = __ballot(v != 0.f);
                if (v != 0.f) {
                    int pos = cnt + __popcll(mask & ((1ull << l) - 1ull));
                    nbr[i * NN + pos] = j;
                }
                cnt += __popcll(mask);
            }
            if (l == 0) nbr_cnt[i] = cnt;
        }
    } else {
        // bias_full[384]
        int half = tid >> 7, n = tid & 127;
        const float* w1col = attw1 + (size_t)(half * DD) * DD + n;
        float acc = 0.f;
#pragma unroll 8
        for (int k = 0; k < DD; ++k) acc += bias[k] * w1col[(size_t)k * DD];
        if (half) acc += attb1[n];
        bias_full[DD + tid] = acc;
        if (tid < DD) bias_full[tid] = bias[tid];
    }
}

// ================= Kernel 1: fused GEMM via MFMA ===========================
// C[4096 x 384] = x @ Bt^T (+bias_full), split-stored to hbuf/abuf/bbuf.
// x loaded fp32 and converted to bf16 fragments in-register (x read once).
__global__ __launch_bounds__(256) void gemm_kernel(
        const float* __restrict__ x, const __bf16* __restrict__ Bt,
        const float* __restrict__ bias_full,
        float* __restrict__ hbuf, float* __restrict__ abuf,
        float* __restrict__ bbuf) {
    int tid = threadIdx.x;
    int w = tid >> 6, l = tid & 63;
    int row0 = blockIdx.x * 16;
    int lrow = l & 15, lk = (l >> 4) * 8;

    // A fragments: lane holds row (l&15), k = (l>>4)*8 + j  (+32 per k-tile)
    const float* abase = x + (size_t)(row0 + lrow) * DD + lk;
    bf16x8 af0, af1, af2, af3;
    {
        float4 u0, u1;
        u0 = *(const float4*)(abase +  0); u1 = *(const float4*)(abase +  4);
        af0[0]=(__bf16)u0.x; af0[1]=(__bf16)u0.y; af0[2]=(__bf16)u0.z; af0[3]=(__bf16)u0.w;
        af0[4]=(__bf16)u1.x; af0[5]=(__bf16)u1.y; af0[6]=(__bf16)u1.z; af0[7]=(__bf16)u1.w;
        u0 = *(const float4*)(abase + 32); u1 = *(const float4*)(abase + 36);
        af1[0]=(__bf16)u0.x; af1[1]=(__bf16)u0.y; af1[2]=(__bf16)u0.z; af1[3]=(__bf16)u0.w;
        af1[4]=(__bf16)u1.x; af1[5]=(__bf16)u1.y; af1[6]=(__bf16)u1.z; af1[7]=(__bf16)u1.w;
        u0 = *(const float4*)(abase + 64); u1 = *(const float4*)(abase + 68);
        af2[0]=(__bf16)u0.x; af2[1]=(__bf16)u0.y; af2[2]=(__bf16)u0.z; af2[3]=(__bf16)u0.w;
        af2[4]=(__bf16)u1.x; af2[5]=(__bf16)u1.y; af2[6]=(__bf16)u1.z; af2[7]=(__bf16)u1.w;
        u0 = *(const float4*)(abase + 96); u1 = *(const float4*)(abase + 100);
        af3[0]=(__bf16)u0.x; af3[1]=(__bf16)u0.y; af3[2]=(__bf16)u0.z; af3[3]=(__bf16)u0.w;
        af3[4]=(__bf16)u1.x; af3[5]=(__bf16)u1.y; af3[6]=(__bf16)u1.z; af3[7]=(__bf16)u1.w;
    }

#pragma unroll
    for (int t6 = 0; t6 < 6; ++t6) {
        int t = w + 4 * t6;
        int n0 = t * 16;
        const __bf16* bbase = Bt + (size_t)(n0 + lrow) * DD + lk;
        f32x4 acc = {0.f, 0.f, 0.f, 0.f};
        acc = __builtin_amdgcn_mfma_f32_16x16x32_bf16(af0, *(const bf16x8*)(bbase),      acc, 0, 0, 0);
        acc = __builtin_amdgcn_mfma_f32_16x16x32_bf16(af1, *(const bf16x8*)(bbase + 32), acc, 0, 0, 0);
        acc = __builtin_amdgcn_mfma_f32_16x16x32_bf16(af2, *(const bf16x8*)(bbase + 64), acc, 0, 0, 0);
        acc = __builtin_amdgcn_mfma_f32_16x16x32_bf16(af3, *(const bf16x8*)(bbase + 96), acc, 0, 0, 0);

        float bb = bias_full[n0 + lrow];
        float* dst = (t < 8) ? hbuf : (t < 16) ? abuf : bbuf;
        int nloc = (n0 & 127) + lrow;           // C/D: col = lane&15
        int rbase = row0 + (l >> 4) * 4;        //      row = (lane>>4)*4 + reg
        dst[(size_t)(rbase + 0) * DD + nloc] = acc[0] + bb;
        dst[(size_t)(rbase + 1) * DD + nloc] = acc[1] + bb;
        dst[(size_t)(rbase + 2) * DD + nloc] = acc[2] + bb;
        dst[(size_t)(rbase + 3) * DD + nloc] = acc[3] + bb;
    }
}

// ================= Kernel 2: sparse attn + LayerNorm + ReLU ================
// 4 waves/block, one (node, bt) per wave; lane l owns dims l and l+64.
__global__ __launch_bounds__(256) void attn_kernel(
        const float* __restrict__ hbuf, const float* __restrict__ abuf,
        const float* __restrict__ bbuf, const float* __restrict__ x,
        const int* __restrict__ nbr, const int* __restrict__ nbr_cnt,
        const float* __restrict__ w2, const float* __restrict__ gamma,
        const float* __restrict__ beta, float* __restrict__ out) {
    int tid = threadIdx.x;
    int w = tid >> 6, l = tid & 63;
    int i = blockIdx.x * 4 + w;
    int bt = blockIdx.y;

    int cnt = nbr_cnt[i];
    int jreg = nbr[i * NN + l];     // lane l holds neighbor l's index (valid l<cnt)

    const float* arow = abuf + (size_t)(bt * NN + i) * DD;
    float a0 = arow[l], a1 = arow[l + 64];
    float w20 = w2[l],  w21 = w2[l + 64];
    const float* bbase = bbuf + (size_t)bt * NN * DD;

    // ---- scores: 4 neighbors per iteration (4 independent reduce chains) ----
    float m = -3.0e38f, myp = 0.f;
    int c = 0;
    for (; c + 3 < cnt; c += 4) {
        int j0 = __shfl(jreg, c);
        int j1 = __shfl(jreg, c + 1);
        int j2 = __shfl(jreg, c + 2);
        int j3 = __shfl(jreg, c + 3);
        const float* B0 = bbase + (size_t)j0 * DD;
        const float* B1 = bbase + (size_t)j1 * DD;
        const float* B2 = bbase + (size_t)j2 * DD;
        const float* B3 = bbase + (size_t)j3 * DD;
        float p0 = LREL(a0 + B0[l]) * w20 + LREL(a1 + B0[l + 64]) * w21;
        float p1 = LREL(a0 + B1[l]) * w20 + LREL(a1 + B1[l + 64]) * w21;
        float p2 = LREL(a0 + B2[l]) * w20 + LREL(a1 + B2[l + 64]) * w21;
        float p3 = LREL(a0 + B3[l]) * w20 + LREL(a1 + B3[l + 64]) * w21;
#pragma unroll
        for (int off = 32; off; off >>= 1) {
            p0 += __shfl_xor(p0, off);
            p1 += __shfl_xor(p1, off);
            p2 += __shfl_xor(p2, off);
            p3 += __shfl_xor(p3, off);
        }
        myp = (l == c)     ? p0 : myp;
        myp = (l == c + 1) ? p1 : myp;
        myp = (l == c + 2) ? p2 : myp;
        myp = (l == c + 3) ? p3 : myp;
        m = fmaxf(m, fmaxf(fmaxf(p0, p1), fmaxf(p2, p3)));
    }
    for (; c < cnt; ++c) {
        int j0 = __shfl(jreg, c);
        const float* B0 = bbase + (size_t)j0 * DD;
        float p0 = LREL(a0 + B0[l]) * w20 + LREL(a1 + B0[l + 64]) * w21;
#pragma unroll
        for (int off = 32; off; off >>= 1) p0 += __shfl_xor(p0, off);
        myp = (l == c) ? p0 : myp;
        m = fmaxf(m, p0);
    }

    float wgt = (l < cnt) ? expf(myp - m) : 0.f;
    float dsum = wgt;
#pragma unroll
    for (int off = 32; off; off >>= 1) dsum += __shfl_xor(dsum, off);
    float inv = 1.f / dsum;

    // ---- aggregate: 4 neighbors per iteration ----
    const float* hbase = hbuf + (size_t)bt * NN * DD;
    float acc0 = 0.f, acc1 = 0.f;
    c = 0;
    for (; c + 3 < cnt; c += 4) {
        float wc0 = __shfl(wgt, c),     wc1 = __shfl(wgt, c + 1);
        float wc2 = __shfl(wgt, c + 2), wc3 = __shfl(wgt, c + 3);
        int j0 = __shfl(jreg, c),     j1 = __shfl(jreg, c + 1);
        int j2 = __shfl(jreg, c + 2), j3 = __shfl(jreg, c + 3);
        const float* H0 = hbase + (size_t)j0 * DD;
        const float* H1 = hbase + (size_t)j1 * DD;
        const float* H2 = hbase + (size_t)j2 * DD;
        const float* H3 = hbase + (size_t)j3 * DD;
        acc0 += wc0 * H0[l]      + wc1 * H1[l]      + wc2 * H2[l]      + wc3 * H3[l];
        acc1 += wc0 * H0[l + 64] + wc1 * H1[l + 64] + wc2 * H2[l + 64] + wc3 * H3[l + 64];
    }
    for (; c < cnt; ++c) {
        float wc = __shfl(wgt, c);
        int j = __shfl(jreg, c);
        const float* H = hbase + (size_t)j * DD;
        acc0 += wc * H[l];
        acc1 += wc * H[l + 64];
    }

    // ---- residual + LayerNorm + ReLU ----
    const float* xrow = x + (size_t)(bt * NN + i) * DD;
    float y0 = acc0 * inv + xrow[l];
    float y1 = acc1 * inv + xrow[l + 64];

    float s = y0 + y1;
#pragma unroll
    for (int off = 32; off; off >>= 1) s += __shfl_xor(s, off);
    float mu = s * (1.0f / 128.0f);
    float v0 = y0 - mu, v1 = y1 - mu;
    float vs = v0 * v0 + v1 * v1;
#pragma unroll
    for (int off = 32; off; off >>= 1) vs += __shfl_xor(vs, off);
    float rstd = rsqrtf(vs * (1.0f / 128.0f) + 1e-5f);

    float o0 = v0 * rstd * gamma[l]      + beta[l];
    float o1 = v1 * rstd * gamma[l + 64] + beta[l + 64];

    float* orow = out + (size_t)(bt * NN + i) * DD;
    orow[l]      = fmaxf(o0, 0.0f);
    orow[l + 64] = fmaxf(o1, 0.0f);
}

extern "C" void kernel_launch(void* const* d_in, const int* in_sizes, int n_in,
                              void* d_out, int out_size, void* d_ws, size_t ws_size,
                              hipStream_t stream) {
    const float* x      = (const float*)d_in[0];
    const float* adj    = (const float*)d_in[1];
    const float* weight = (const float*)d_in[2];
    const float* bias   = (const float*)d_in[3];
    const float* attw1  = (const float*)d_in[4];
    const float* attb1  = (const float*)d_in[5];
    const float* attw2  = (const float*)d_in[6];
    // d_in[7] = att_b2: uniform score shift -> cancels in softmax
    const float* gamma  = (const float*)d_in[8];
    const float* beta   = (const float*)d_in[9];
    float* out = (float*)d_out;

    char* p = (char*)d_ws;
    float* hbuf = (float*)p;          p += (size_t)MROWS * DD * 4;
    float* abuf = (float*)p;          p += (size_t)MROWS * DD * 4;
    float* bbuf = (float*)p;          p += (size_t)MROWS * DD * 4;
    float* bias_full = (float*)p;     p += 512 * 4;
    __bf16* Bt = (__bf16*)p;          p += (size_t)384 * DD * 2;
    int* nbr     = (int*)p;           p += (size_t)NN * NN * 4;
    int* nbr_cnt = (int*)p;

    prep_kernel<<<PREP_BLOCKS, 256, 0, stream>>>(weight, bias, attw1, attb1, adj,
                                                 Bt, bias_full, nbr, nbr_cnt);
    gemm_kernel<<<MROWS / 16, 256, 0, stream>>>(x, Bt, bias_full, hbuf, abuf, bbuf);
    attn_kernel<<<dim3(NN / 4, BT), 256, 0, stream>>>(hbuf, abuf, bbuf, x, nbr, nbr_cnt,
                                                      attw2, gamma, beta, out);
}